// Round 4
// baseline (395.549 us; speedup 1.0000x reference)
//
#include <hip/hip_runtime.h>
#include <hip/hip_cooperative_groups.h>
#include <math.h>

namespace cg = cooperative_groups;

// Problem shapes (fixed by reference setup_inputs)
#define B    256
#define S    196
#define D    1024
#define P    512
#define L    8
#define TOPK 4

#define KSPLIT 8          // split-K for sim
#define RPG 49            // rows per group in phase A (S = 4 * 49)
#define KK 16             // k-step in sim tile
#define PKB 32            // fallback: pk-norm blocks
#define PK_PER_BLOCK 16

// ---------------------------------------------------------------------------
// Cooperative single-launch kernel. grid(256), block(1024), 1 block/CU.
// Phase A: block b -> mean(x[b]) + |m|^2 -> qm, s_alpha (LDS); waves 12/13
//          also compute beta[2b],beta[2b+1] = rsqrt(|pk_p|^2).
// grid.sync
// Phase B: remap 256 blocks -> (bx,by,bz) 4x8x8; 64x64 tile, 2x2 micro,
//          k-chunk 128 per bz. Writes simp[z][b][p] (raw dot partials).
// grid.sync
// Phase C: block b selects its TOPK indices (split-K reduce, alpha*beta
//          scale, Gumbel argmax with in-register mask-out) -- same fp32
//          order as the verified multi-kernel version.
// Phase D: block b gathers its 4 prompt rows -> out[b] (128 KB, 16 waves).
// ---------------------------------------------------------------------------
__global__ __launch_bounds__(1024, 4) void fused_all_kernel(
    const float* __restrict__ x, const float* __restrict__ pk,
    const float* __restrict__ gu, const float* __restrict__ prompt,
    float* __restrict__ out, float* __restrict__ simp,
    float* __restrict__ qm, float* __restrict__ beta) {
  cg::grid_group grid = cg::this_grid();
  const int blk = blockIdx.x;
  const int t = threadIdx.x;
  const int lane = t & 63;
  const int w = t >> 6;   // 0..15

  __shared__ float4 red[3][256];   // 12 KB (phase A)
  __shared__ float wsum[4];
  __shared__ float s_alpha;
  __shared__ float As[KK][65];     // 4.1 KB (phase B)
  __shared__ float Bs[KK][65];
  __shared__ float wval[8];
  __shared__ int   widx[8];
  __shared__ int   ssel[TOPK];

  // ---------------- Phase A: mean + norms ----------------
  {
    const int g = t >> 8;   // row group 0..3
    const int c = t & 255;  // d-chunk (4 floats)
    const float* xb = x + (size_t)blk * S * D + (size_t)g * RPG * D + c * 4;
    float4 acc = make_float4(0.f, 0.f, 0.f, 0.f);
#pragma unroll 7
    for (int s = 0; s < RPG; ++s) {
      float4 v = *(const float4*)(xb + (size_t)s * D);
      acc.x += v.x; acc.y += v.y; acc.z += v.z; acc.w += v.w;
    }
    if (g > 0) red[g - 1][c] = acc;
    __syncthreads();
    if (g == 0) {
      float4 r0 = red[0][c], r1 = red[1][c], r2 = red[2][c];
      acc.x += r0.x + r1.x + r2.x;
      acc.y += r0.y + r1.y + r2.y;
      acc.z += r0.z + r1.z + r2.z;
      acc.w += r0.w + r1.w + r2.w;
      const float inv = 1.0f / (float)S;
      acc.x *= inv; acc.y *= inv; acc.z *= inv; acc.w *= inv;
      *(float4*)(qm + (size_t)blk * D + c * 4) = acc;
      float ss =
          acc.x * acc.x + acc.y * acc.y + acc.z * acc.z + acc.w * acc.w;
      for (int off = 32; off > 0; off >>= 1) ss += __shfl_down(ss, off, 64);
      if (lane == 0) wsum[w] = ss;   // w = 0..3 here
    } else if (w == 12 || w == 13) {
      // pk-norm: 256 blocks x 2 rows = 512 rows, balanced across grid
      const int p = blk * 2 + (w - 12);
      const float* kp = pk + (size_t)p * D;
      float ss = 0.f;
#pragma unroll
      for (int j = 0; j < 4; ++j) {
        float4 v = *(const float4*)(kp + lane * 4 + j * 256);
        ss += v.x * v.x + v.y * v.y + v.z * v.z + v.w * v.w;
      }
      for (int off = 32; off > 0; off >>= 1) ss += __shfl_down(ss, off, 64);
      if (lane == 0) beta[p] = rsqrtf(fmaxf(ss, 1e-12f));
    }
    __syncthreads();
    if (t == 0)
      s_alpha =
          rsqrtf(fmaxf(wsum[0] + wsum[1] + wsum[2] + wsum[3], 1e-12f));
  }
  grid.sync();

  // ---------------- Phase B: sim partials (raw dot) ----------------
  {
    const int bz = blk >> 5;          // 0..7 (k-split)
    const int by = (blk >> 2) & 7;    // 0..7 (p tile)
    const int bx = blk & 3;           // 0..3 (b tile)
    const int b0 = bx * 64, p0 = by * 64, k0 = bz * (D / KSPLIT);
    const int lr = t >> 4;  // 0..63 tile row (loader)
    const int lk = t & 15;  // 0..15 k (loader)
    const int tx = t & 31;  // p/2 (compute)
    const int ty = t >> 5;  // b/2 (compute)
    float a00 = 0.f, a01 = 0.f, a10 = 0.f, a11 = 0.f;
    for (int kt = 0; kt < D / KSPLIT; kt += KK) {
      As[lk][lr] = qm[(size_t)(b0 + lr) * D + k0 + kt + lk];
      Bs[lk][lr] = pk[(size_t)(p0 + lr) * D + k0 + kt + lk];
      __syncthreads();
#pragma unroll
      for (int kk = 0; kk < KK; ++kk) {
        float av0 = As[kk][ty * 2], av1 = As[kk][ty * 2 + 1];
        float bv0 = Bs[kk][tx * 2], bv1 = Bs[kk][tx * 2 + 1];
        a00 += av0 * bv0; a01 += av0 * bv1;
        a10 += av1 * bv0; a11 += av1 * bv1;
      }
      __syncthreads();
    }
    float* sp = simp + ((size_t)bz * B + b0 + ty * 2) * P + p0 + tx * 2;
    sp[0] = a00; sp[1] = a01; sp[P] = a10; sp[P + 1] = a11;
  }
  grid.sync();

  // ---------------- Phase C: select (threads 0..511) ----------------
  float cval = 0.f;
  float gn[TOPK];
  if (t < P) {
#pragma unroll
    for (int z = 0; z < KSPLIT; ++z)
      cval += simp[((size_t)z * B + blk) * P + t];
    cval *= s_alpha * beta[t];
#pragma unroll
    for (int i = 0; i < TOPK; ++i) {
      float u = gu[((size_t)i * B + blk) * P + t];
      gn[i] = -logf(-logf(u + 1e-10f) + 1e-10f);
    }
  }
  for (int i = 0; i < TOPK; ++i) {
    if (t < P) {
      float v = cval + gn[i];
      int idx = t;
      for (int off = 32; off > 0; off >>= 1) {
        float ov = __shfl_down(v, off, 64);
        int oi = __shfl_down(idx, off, 64);
        if (ov > v || (ov == v && oi < idx)) { v = ov; idx = oi; }
      }
      if (lane == 0) { wval[w] = v; widx[w] = idx; }
    }
    __syncthreads();
    if (t == 0) {
      float bv = wval[0]; int bi = widx[0];
#pragma unroll
      for (int k2 = 1; k2 < 8; ++k2)
        if (wval[k2] > bv || (wval[k2] == bv && widx[k2] < bi)) {
          bv = wval[k2]; bi = widx[k2];
        }
      ssel[i] = bi;
    }
    __syncthreads();
    if (t < P && t == ssel[i]) cval -= 1000.f;  // hard mask-out
  }

  // ---------------- Phase D: gather (all 16 waves) ----------------
#pragma unroll
  for (int i = 0; i < TOPK; ++i) {
    const int p = ssel[i];
    const float4* src = (const float4*)(prompt + (size_t)p * L * D);
    float4* dst = (float4*)(out + ((size_t)blk * (TOPK * L) + i * L) * D);
    dst[t] = src[t];
    dst[t + 1024] = src[t + 1024];
  }
}

// ===========================================================================
// Fallback path: the verified r3 4-kernel pipeline (used only if the
// cooperative launch is rejected, e.g. unsupported under graph capture).
// ===========================================================================
__global__ __launch_bounds__(1024) void query_norm_kernel(
    const float* __restrict__ x, const float* __restrict__ pk,
    float* __restrict__ qm, float* __restrict__ alpha,
    float* __restrict__ beta) {
  const int t = threadIdx.x;
  const int lane = t & 63;
  const int w = t >> 6;

  if (blockIdx.x >= B) {
    const int p = (blockIdx.x - B) * PK_PER_BLOCK + w;
    const float* kp = pk + (size_t)p * D;
    float ss = 0.f;
#pragma unroll
    for (int j = 0; j < 4; ++j) {
      float4 v = *(const float4*)(kp + lane * 4 + j * 256);
      ss += v.x * v.x + v.y * v.y + v.z * v.z + v.w * v.w;
    }
    for (int off = 32; off > 0; off >>= 1) ss += __shfl_down(ss, off, 64);
    if (lane == 0) beta[p] = rsqrtf(fmaxf(ss, 1e-12f));
    return;
  }

  const int b = blockIdx.x;
  const int g = t >> 8;
  const int c = t & 255;
  const float* xb = x + (size_t)b * S * D + (size_t)g * RPG * D + c * 4;

  float4 acc = make_float4(0.f, 0.f, 0.f, 0.f);
#pragma unroll 7
  for (int s = 0; s < RPG; ++s) {
    float4 v = *(const float4*)(xb + (size_t)s * D);
    acc.x += v.x; acc.y += v.y; acc.z += v.z; acc.w += v.w;
  }

  __shared__ float4 red[3][256];
  __shared__ float wsum[4];
  if (g > 0) red[g - 1][c] = acc;
  __syncthreads();

  if (g == 0) {
    float4 r0 = red[0][c], r1 = red[1][c], r2 = red[2][c];
    acc.x += r0.x + r1.x + r2.x;
    acc.y += r0.y + r1.y + r2.y;
    acc.z += r0.z + r1.z + r2.z;
    acc.w += r0.w + r1.w + r2.w;
    const float inv = 1.0f / (float)S;
    acc.x *= inv; acc.y *= inv; acc.z *= inv; acc.w *= inv;
    *(float4*)(qm + (size_t)b * D + c * 4) = acc;
    float ss = acc.x * acc.x + acc.y * acc.y + acc.z * acc.z + acc.w * acc.w;
    for (int off = 32; off > 0; off >>= 1) ss += __shfl_down(ss, off, 64);
    if (lane == 0) wsum[w] = ss;
  }
  __syncthreads();
  if (t == 0)
    alpha[b] = rsqrtf(fmaxf(wsum[0] + wsum[1] + wsum[2] + wsum[3], 1e-12f));
}

__global__ __launch_bounds__(256) void sim_kernel(
    const float* __restrict__ qm, const float* __restrict__ pk,
    float* __restrict__ simp) {
  const int b0 = blockIdx.x * 64;
  const int p0 = blockIdx.y * 64;
  const int z  = blockIdx.z;
  const int k0 = z * (D / KSPLIT);
  const int t = threadIdx.x;
  const int tx = t & 15;
  const int ty = t >> 4;

  __shared__ float As2[KK][68];
  __shared__ float Bs2[KK][68];

  float acc[4][4];
#pragma unroll
  for (int i = 0; i < 4; ++i)
#pragma unroll
    for (int j = 0; j < 4; ++j) acc[i][j] = 0.f;

  const int rr = t >> 2;
  const int k4 = (t & 3) * 4;

  for (int kt = 0; kt < D / KSPLIT; kt += KK) {
    float4 a = *(const float4*)(qm + (size_t)(b0 + rr) * D + k0 + kt + k4);
    float4 bb = *(const float4*)(pk + (size_t)(p0 + rr) * D + k0 + kt + k4);
    As2[k4 + 0][rr] = a.x; As2[k4 + 1][rr] = a.y;
    As2[k4 + 2][rr] = a.z; As2[k4 + 3][rr] = a.w;
    Bs2[k4 + 0][rr] = bb.x; Bs2[k4 + 1][rr] = bb.y;
    Bs2[k4 + 2][rr] = bb.z; Bs2[k4 + 3][rr] = bb.w;
    __syncthreads();
#pragma unroll
    for (int kk = 0; kk < KK; ++kk) {
      float4 av = *(const float4*)&As2[kk][ty * 4];
      float4 bv = *(const float4*)&Bs2[kk][tx * 4];
      acc[0][0] += av.x * bv.x; acc[0][1] += av.x * bv.y;
      acc[0][2] += av.x * bv.z; acc[0][3] += av.x * bv.w;
      acc[1][0] += av.y * bv.x; acc[1][1] += av.y * bv.y;
      acc[1][2] += av.y * bv.z; acc[1][3] += av.y * bv.w;
      acc[2][0] += av.z * bv.x; acc[2][1] += av.z * bv.y;
      acc[2][2] += av.z * bv.z; acc[2][3] += av.z * bv.w;
      acc[3][0] += av.w * bv.x; acc[3][1] += av.w * bv.y;
      acc[3][2] += av.w * bv.z; acc[3][3] += av.w * bv.w;
    }
    __syncthreads();
  }
#pragma unroll
  for (int i = 0; i < 4; ++i)
#pragma unroll
    for (int j = 0; j < 4; ++j)
      simp[((size_t)z * B + b0 + ty * 4 + i) * P + p0 + tx * 4 + j] =
          acc[i][j];
}

__global__ __launch_bounds__(512) void select_kernel(
    const float* __restrict__ simp, const float* __restrict__ alpha,
    const float* __restrict__ beta, const float* __restrict__ gu,
    int* __restrict__ sidx) {
  const int b = blockIdx.x;
  const int t = threadIdx.x;
  const int lane = t & 63, wv = t >> 6;

  float c = 0.f;
#pragma unroll
  for (int z = 0; z < KSPLIT; ++z)
    c += simp[((size_t)z * B + b) * P + t];
  c *= alpha[b] * beta[t];

  float g[TOPK];
#pragma unroll
  for (int i = 0; i < TOPK; ++i) {
    float u = gu[((size_t)i * B + b) * P + t];
    g[i] = -logf(-logf(u + 1e-10f) + 1e-10f);
  }

  __shared__ float wval[8];
  __shared__ int   widx[8];
  __shared__ int   ssel[TOPK];

  for (int i = 0; i < TOPK; ++i) {
    float v = c + g[i];
    int idx = t;
    for (int off = 32; off > 0; off >>= 1) {
      float ov = __shfl_down(v, off, 64);
      int oi = __shfl_down(idx, off, 64);
      if (ov > v || (ov == v && oi < idx)) { v = ov; idx = oi; }
    }
    if (lane == 0) { wval[wv] = v; widx[wv] = idx; }
    __syncthreads();
    if (t == 0) {
      float bv = wval[0]; int bi = widx[0];
#pragma unroll
      for (int k = 1; k < 8; ++k)
        if (wval[k] > bv || (wval[k] == bv && widx[k] < bi)) {
          bv = wval[k]; bi = widx[k];
        }
      ssel[i] = bi;
    }
    __syncthreads();
    if (t == ssel[i]) c -= 1000.0f;
  }
  if (t < TOPK) sidx[b * TOPK + t] = ssel[t];
}

__global__ __launch_bounds__(256) void gather_kernel(
    const int* __restrict__ sidx, const float* __restrict__ prompt,
    float* __restrict__ out) {
  const int bi = blockIdx.x;
  const int h = blockIdx.y;
  const int t = threadIdx.x;
  const int p = sidx[bi];
  const float4* src =
      (const float4*)(prompt + (size_t)p * L * D) + h * 1024;
  float4* dst = (float4*)(out + (size_t)bi * (L * D)) + h * 1024;
#pragma unroll
  for (int c = 0; c < 4; ++c)
    dst[c * 256 + t] = src[c * 256 + t];
}

// ---------------------------------------------------------------------------
extern "C" void kernel_launch(void* const* d_in, const int* in_sizes, int n_in,
                              void* d_out, int out_size, void* d_ws,
                              size_t ws_size, hipStream_t stream) {
  const float* x_embed    = (const float*)d_in[0];  // [B,S,D]
  const float* prompt     = (const float*)d_in[1];  // [P,L,D]
  const float* prompt_key = (const float*)d_in[2];  // [P,D]
  const float* gumbel_u   = (const float*)d_in[3];  // [TOPK,B,P]
  float* out = (float*)d_out;                       // [B,TOPK*L,D]

  // ws layout (~5.3 MB): simp | qm | alpha | beta | sidx
  float* simp  = (float*)d_ws;                     // KSPLIT*B*P = 1048576 f
  float* qm    = simp + (size_t)KSPLIT * B * P;    // B*D        =  262144 f
  float* alpha = qm + (size_t)B * D;               // B (fallback only)
  float* beta  = alpha + B;                        // P
  int*   sidx  = (int*)(beta + P);                 // B*TOPK (fallback only)

  void* args[] = {(void*)&x_embed, (void*)&prompt_key, (void*)&gumbel_u,
                  (void*)&prompt,  (void*)&out,        (void*)&simp,
                  (void*)&qm,      (void*)&beta};
  hipError_t err = hipLaunchCooperativeKernel(
      (const void*)fused_all_kernel, dim3(B), dim3(1024), args, 0, stream);
  if (err != hipSuccess) {
    // Fallback: verified r3 multi-kernel pipeline.
    query_norm_kernel<<<B + PKB, 1024, 0, stream>>>(x_embed, prompt_key, qm,
                                                    alpha, beta);
    sim_kernel<<<dim3(B / 64, P / 64, KSPLIT), 256, 0, stream>>>(
        qm, prompt_key, simp);
    select_kernel<<<B, 512, 0, stream>>>(simp, alpha, beta, gumbel_u, sidx);
    gather_kernel<<<dim3(B * TOPK, 2), 256, 0, stream>>>(sidx, prompt, out);
  }
}

// Round 5
// 332.199 us; speedup vs baseline: 1.1907x; 1.1907x over previous
//
#include <hip/hip_runtime.h>
#include <math.h>

// Problem shapes (fixed by reference setup_inputs)
#define B    256
#define S    196
#define D    1024
#define P    512
#define L    8
#define TOPK 4

#define SSPLIT 7            // S = 7 * 28
#define SCHUNK (S / SSPLIT) // 28
#define KSPLIT 8            // split-K for sim
#define KK 16               // k-step in sim tile
#define NPART_BLK (B * SSPLIT)  // 1792 partial-sum blocks
#define BETA_BLK 32             // appended pk-norm blocks (16 rows each)

// ---------------------------------------------------------------------------
// Kernel 1: balanced partial sums + pk norms. grid(1824), block(256).
// blocks [0,1792): r0-proven streaming partial sum over 28 rows (205 MB
//   HBM read, ~7.1 blocks/CU, 28 waves/CU -> BW-bound, no tail).
// blocks [1792,1824): 16 pk rows each -> beta[p] = rsqrt(max(|pk_p|^2,eps)).
// NOTE: partials are SUMS (no 1/S) -- the 1/S cancels in the cosine sim.
// ---------------------------------------------------------------------------
__global__ __launch_bounds__(256) void k1_partial_beta_kernel(
    const float* __restrict__ x, const float* __restrict__ pk,
    float* __restrict__ part, float* __restrict__ beta) {
  const int blk = blockIdx.x;
  const int t = threadIdx.x;

  if (blk < NPART_BLK) {
    const int b = blk / SSPLIT;
    const int j = blk % SSPLIT;
    const float* xb =
        x + (size_t)b * S * D + (size_t)j * SCHUNK * D + t * 4;
    float4 acc = make_float4(0.f, 0.f, 0.f, 0.f);
#pragma unroll 4
    for (int s = 0; s < SCHUNK; ++s) {
      float4 v = *(const float4*)(xb + (size_t)s * D);
      acc.x += v.x; acc.y += v.y; acc.z += v.z; acc.w += v.w;
    }
    *(float4*)(part + ((size_t)b * SSPLIT + j) * D + t * 4) = acc;
  } else {
    const int pb = blk - NPART_BLK;   // 0..31
    const int lane = t & 63, w = t >> 6;  // 4 waves
#pragma unroll
    for (int r = 0; r < 4; ++r) {
      const int p = pb * 16 + w * 4 + r;
      const float* kp = pk + (size_t)p * D;
      float ss = 0.f;
#pragma unroll
      for (int j = 0; j < 4; ++j) {
        float4 v = *(const float4*)(kp + lane * 4 + j * 256);
        ss += v.x * v.x + v.y * v.y + v.z * v.z + v.w * v.w;
      }
      for (int off = 32; off > 0; off >>= 1) ss += __shfl_down(ss, off, 64);
      if (lane == 0) beta[p] = rsqrtf(fmaxf(ss, 1e-12f));
    }
  }
}

// ---------------------------------------------------------------------------
// Kernel 2: raw-dot partials = (sum_x) @ pk^T with the 7-way partial
// reduction folded into the A-tile staging (part is L2-resident; +57 MB L2
// traffic ~1.6 us, removes the qm round-trip + finalize kernel).
// grid(B/64, P/64, KSPLIT), block(256), 64x64 tile, 4x4 micro.
// ---------------------------------------------------------------------------
__global__ __launch_bounds__(256) void sim_kernel(
    const float* __restrict__ part, const float* __restrict__ pk,
    float* __restrict__ simp) {
  const int b0 = blockIdx.x * 64;
  const int p0 = blockIdx.y * 64;
  const int z  = blockIdx.z;
  const int k0 = z * (D / KSPLIT);  // 128 per split
  const int t = threadIdx.x;
  const int tx = t & 15;   // p micro index
  const int ty = t >> 4;   // b micro index

  __shared__ float As[KK][68];  // [k][b]  (A = row-sums of x)
  __shared__ float Bs[KK][68];  // [k][p]

  float acc[4][4];
#pragma unroll
  for (int i = 0; i < 4; ++i)
#pragma unroll
    for (int j = 0; j < 4; ++j) acc[i][j] = 0.f;

  const int rr = t >> 2;        // 0..63 : row within tile
  const int k4 = (t & 3) * 4;   // 0,4,8,12

  for (int kt = 0; kt < D / KSPLIT; kt += KK) {
    float4 a = make_float4(0.f, 0.f, 0.f, 0.f);
    const float* pb = part + ((size_t)(b0 + rr) * SSPLIT) * D + k0 + kt + k4;
#pragma unroll
    for (int j = 0; j < SSPLIT; ++j) {
      float4 v = *(const float4*)(pb + (size_t)j * D);
      a.x += v.x; a.y += v.y; a.z += v.z; a.w += v.w;
    }
    float4 bb = *(const float4*)(pk + (size_t)(p0 + rr) * D + k0 + kt + k4);
    As[k4 + 0][rr] = a.x; As[k4 + 1][rr] = a.y;
    As[k4 + 2][rr] = a.z; As[k4 + 3][rr] = a.w;
    Bs[k4 + 0][rr] = bb.x; Bs[k4 + 1][rr] = bb.y;
    Bs[k4 + 2][rr] = bb.z; Bs[k4 + 3][rr] = bb.w;
    __syncthreads();
#pragma unroll
    for (int kk = 0; kk < KK; ++kk) {
      float4 av = *(const float4*)&As[kk][ty * 4];
      float4 bv = *(const float4*)&Bs[kk][tx * 4];
      acc[0][0] += av.x * bv.x; acc[0][1] += av.x * bv.y;
      acc[0][2] += av.x * bv.z; acc[0][3] += av.x * bv.w;
      acc[1][0] += av.y * bv.x; acc[1][1] += av.y * bv.y;
      acc[1][2] += av.y * bv.z; acc[1][3] += av.y * bv.w;
      acc[2][0] += av.z * bv.x; acc[2][1] += av.z * bv.y;
      acc[2][2] += av.z * bv.z; acc[2][3] += av.z * bv.w;
      acc[3][0] += av.w * bv.x; acc[3][1] += av.w * bv.y;
      acc[3][2] += av.w * bv.z; acc[3][3] += av.w * bv.w;
    }
    __syncthreads();
  }
#pragma unroll
  for (int i = 0; i < 4; ++i)
#pragma unroll
    for (int j = 0; j < 4; ++j)
      simp[((size_t)z * B + b0 + ty * 4 + i) * P + p0 + tx * 4 + j] =
          acc[i][j];
}

// ---------------------------------------------------------------------------
// Kernel 3: select. grid(B), block(512).
// alpha' = rsqrt(max(|sum_x|^2, S^2*1e-12)) computed in-block from part
// (28 KB L2 read); sim = dotraw * alpha' * beta  (1/S cancelled exactly).
// Then 4 Gumbel argmax rounds with in-register mask-out -> sidx.
// ---------------------------------------------------------------------------
__global__ __launch_bounds__(512) void select_kernel(
    const float* __restrict__ simp, const float* __restrict__ part,
    const float* __restrict__ beta, const float* __restrict__ gu,
    int* __restrict__ sidx) {
  const int b = blockIdx.x;
  const int t = threadIdx.x;  // == pool index p
  const int lane = t & 63, wv = t >> 6;

  __shared__ float wval[8];
  __shared__ int   widx[8];
  __shared__ int   ssel[TOPK];
  __shared__ float s_alpha;

  // ---- alpha' from partial sums ----
  float sq = 0.f;
#pragma unroll
  for (int d = t; d < D; d += 512) {  // 2 iterations
    float s7 = 0.f;
#pragma unroll
    for (int j = 0; j < SSPLIT; ++j)
      s7 += part[((size_t)b * SSPLIT + j) * D + d];
    sq += s7 * s7;
  }
  for (int off = 32; off > 0; off >>= 1) sq += __shfl_down(sq, off, 64);
  if (lane == 0) wval[wv] = sq;
  __syncthreads();
  if (t == 0) {
    float tot = 0.f;
#pragma unroll
    for (int k = 0; k < 8; ++k) tot += wval[k];
    // S^2 * 1e-12 = 196^2 * 1e-12 = 3.8416e-8 (exact algebra w/ reference)
    s_alpha = rsqrtf(fmaxf(tot, 3.8416e-8f));
  }
  __syncthreads();

  // ---- split-K reduce + scale + gumbel ----
  float c = 0.f;
#pragma unroll
  for (int z = 0; z < KSPLIT; ++z)
    c += simp[((size_t)z * B + b) * P + t];
  c *= s_alpha * beta[t];

  float g[TOPK];
#pragma unroll
  for (int i = 0; i < TOPK; ++i) {
    float u = gu[((size_t)i * B + b) * P + t];
    g[i] = -logf(-logf(u + 1e-10f) + 1e-10f);
  }

  for (int i = 0; i < TOPK; ++i) {
    float v = c + g[i];
    int idx = t;
    for (int off = 32; off > 0; off >>= 1) {
      float ov = __shfl_down(v, off, 64);
      int oi = __shfl_down(idx, off, 64);
      if (ov > v || (ov == v && oi < idx)) { v = ov; idx = oi; }
    }
    if (lane == 0) { wval[wv] = v; widx[wv] = idx; }
    __syncthreads();
    if (t == 0) {
      float bv = wval[0]; int bi = widx[0];
#pragma unroll
      for (int k = 1; k < 8; ++k)
        if (wval[k] > bv || (wval[k] == bv && widx[k] < bi)) {
          bv = wval[k]; bi = widx[k];
        }
      ssel[i] = bi;
    }
    __syncthreads();
    if (t == ssel[i]) c -= 1000.0f;  // hard mask-out, in-register
  }
  if (t < TOPK) sidx[b * TOPK + t] = ssel[t];
}

// ---------------------------------------------------------------------------
// Kernel 4: gather. grid(B*TOPK, 2), block(256). 2048 blocks -> 8/CU.
// 32 MB write + 16 MB (L2/L3-resident) read, bit-exact row copies. ~8 us.
// ---------------------------------------------------------------------------
__global__ __launch_bounds__(256) void gather_kernel(
    const int* __restrict__ sidx, const float* __restrict__ prompt,
    float* __restrict__ out) {
  const int bi = blockIdx.x;        // b*TOPK + i
  const int h = blockIdx.y;         // half: 0 or 1
  const int t = threadIdx.x;
  const int p = sidx[bi];
  const float4* src =
      (const float4*)(prompt + (size_t)p * L * D) + h * 1024;
  float4* dst = (float4*)(out + (size_t)bi * (L * D)) + h * 1024;
#pragma unroll
  for (int c = 0; c < 4; ++c)       // 1024 float4 / 256 threads
    dst[c * 256 + t] = src[c * 256 + t];
}

// ---------------------------------------------------------------------------
extern "C" void kernel_launch(void* const* d_in, const int* in_sizes, int n_in,
                              void* d_out, int out_size, void* d_ws,
                              size_t ws_size, hipStream_t stream) {
  const float* x_embed    = (const float*)d_in[0];  // [B,S,D]
  const float* prompt     = (const float*)d_in[1];  // [P,L,D]
  const float* prompt_key = (const float*)d_in[2];  // [P,D]
  const float* gumbel_u   = (const float*)d_in[3];  // [TOPK,B,P]
  float* out = (float*)d_out;                       // [B,TOPK*L,D]

  // ws layout (~11.3 MB): simp | part | beta | sidx
  float* simp = (float*)d_ws;                      // KSPLIT*B*P = 1048576 f
  float* part = simp + (size_t)KSPLIT * B * P;     // B*SSPLIT*D = 1835008 f
  float* beta = part + (size_t)B * SSPLIT * D;     // P
  int*   sidx = (int*)(beta + P);                  // B*TOPK ints

  k1_partial_beta_kernel<<<NPART_BLK + BETA_BLK, 256, 0, stream>>>(
      x_embed, prompt_key, part, beta);
  sim_kernel<<<dim3(B / 64, P / 64, KSPLIT), 256, 0, stream>>>(part,
                                                               prompt_key,
                                                               simp);
  select_kernel<<<B, 512, 0, stream>>>(simp, part, beta, gumbel_u, sidx);
  gather_kernel<<<dim3(B * TOPK, 2), 256, 0, stream>>>(sidx, prompt, out);
}

// Round 6
// 324.208 us; speedup vs baseline: 1.2200x; 1.0246x over previous
//
#include <hip/hip_runtime.h>
#include <math.h>

// Problem shapes (fixed by reference setup_inputs)
#define B    256
#define S    196
#define D    1024
#define P    512
#define L    8
#define TOPK 4

#define KSPLIT 8          // split-K for sim
#define RPG 49            // rows per group in K1 (S = 4 * 49)
#define KK 16             // k-step in sim tile

// ---------------------------------------------------------------------------
// Kernel 1 (tail-free fused mean + both norms): grid(256), block(1024).
// Block b: threads (g,c) sum rows [g*49,(g+1)*49) of d-chunk c; LDS-reduce
// the 4 groups -> qm[b] (mean) + alpha[b] = rsqrt(max(|m|^2,eps)).
// Waves 12/13 (idle after their stream+red write) compute
// beta[2b], beta[2b+1] = rsqrt(max(|pk_p|^2,eps)) -- 256 blocks x 2 = 512.
// Exactly 1 block/CU, 16 waves/CU, no tail blocks. 205 MB read, BW-bound.
// ---------------------------------------------------------------------------
__global__ __launch_bounds__(1024) void query_norm_kernel(
    const float* __restrict__ x, const float* __restrict__ pk,
    float* __restrict__ qm, float* __restrict__ alpha,
    float* __restrict__ beta) {
  const int b = blockIdx.x;
  const int t = threadIdx.x;
  const int lane = t & 63;
  const int w = t >> 6;   // 0..15
  const int g = t >> 8;   // row group 0..3
  const int c = t & 255;  // d-chunk (4 floats)

  const float* xb = x + (size_t)b * S * D + (size_t)g * RPG * D + c * 4;
  float4 acc = make_float4(0.f, 0.f, 0.f, 0.f);
#pragma unroll 7
  for (int s = 0; s < RPG; ++s) {
    float4 v = *(const float4*)(xb + (size_t)s * D);
    acc.x += v.x; acc.y += v.y; acc.z += v.z; acc.w += v.w;
  }

  __shared__ float4 red[3][256];   // 12 KB
  __shared__ float wsum[4];
  if (g > 0) red[g - 1][c] = acc;
  __syncthreads();

  if (g == 0) {
    float4 r0 = red[0][c], r1 = red[1][c], r2 = red[2][c];
    acc.x += r0.x + r1.x + r2.x;
    acc.y += r0.y + r1.y + r2.y;
    acc.z += r0.z + r1.z + r2.z;
    acc.w += r0.w + r1.w + r2.w;
    const float inv = 1.0f / (float)S;
    acc.x *= inv; acc.y *= inv; acc.z *= inv; acc.w *= inv;
    *(float4*)(qm + (size_t)b * D + c * 4) = acc;
    float ss = acc.x * acc.x + acc.y * acc.y + acc.z * acc.z + acc.w * acc.w;
    for (int off = 32; off > 0; off >>= 1) ss += __shfl_down(ss, off, 64);
    if (lane == 0) wsum[w] = ss;   // w = 0..3 here
  } else if (w == 12 || w == 13) {
    // beta path: 2 pk rows per block, overlapped with g==0 finalize
    const int p = b * 2 + (w - 12);
    const float* kp = pk + (size_t)p * D;
    float ss = 0.f;
#pragma unroll
    for (int j = 0; j < 4; ++j) {
      float4 v = *(const float4*)(kp + lane * 4 + j * 256);
      ss += v.x * v.x + v.y * v.y + v.z * v.z + v.w * v.w;
    }
    for (int off = 32; off > 0; off >>= 1) ss += __shfl_down(ss, off, 64);
    if (lane == 0) beta[p] = rsqrtf(fmaxf(ss, 1e-12f));
  }
  __syncthreads();
  if (t == 0)
    alpha[b] = rsqrtf(fmaxf(wsum[0] + wsum[1] + wsum[2] + wsum[3], 1e-12f));
}

// ---------------------------------------------------------------------------
// Kernel 2: raw-dot partials = qm @ pk^T. Unchanged from r3 (proven ~5 us).
// grid(B/64, P/64, KSPLIT), block(256), 64x64 tile, 4x4 micro.
// ---------------------------------------------------------------------------
__global__ __launch_bounds__(256) void sim_kernel(
    const float* __restrict__ qm, const float* __restrict__ pk,
    float* __restrict__ simp) {
  const int b0 = blockIdx.x * 64;
  const int p0 = blockIdx.y * 64;
  const int z  = blockIdx.z;
  const int k0 = z * (D / KSPLIT);  // 128 per split
  const int t = threadIdx.x;
  const int tx = t & 15;   // p micro index
  const int ty = t >> 4;   // b micro index

  __shared__ float As[KK][68];  // [k][b]
  __shared__ float Bs[KK][68];  // [k][p]

  float acc[4][4];
#pragma unroll
  for (int i = 0; i < 4; ++i)
#pragma unroll
    for (int j = 0; j < 4; ++j) acc[i][j] = 0.f;

  const int rr = t >> 2;        // 0..63 : row within tile
  const int k4 = (t & 3) * 4;   // 0,4,8,12

  for (int kt = 0; kt < D / KSPLIT; kt += KK) {
    float4 a = *(const float4*)(qm + (size_t)(b0 + rr) * D + k0 + kt + k4);
    float4 bb = *(const float4*)(pk + (size_t)(p0 + rr) * D + k0 + kt + k4);
    As[k4 + 0][rr] = a.x; As[k4 + 1][rr] = a.y;
    As[k4 + 2][rr] = a.z; As[k4 + 3][rr] = a.w;
    Bs[k4 + 0][rr] = bb.x; Bs[k4 + 1][rr] = bb.y;
    Bs[k4 + 2][rr] = bb.z; Bs[k4 + 3][rr] = bb.w;
    __syncthreads();
#pragma unroll
    for (int kk = 0; kk < KK; ++kk) {
      float4 av = *(const float4*)&As[kk][ty * 4];
      float4 bv = *(const float4*)&Bs[kk][tx * 4];
      acc[0][0] += av.x * bv.x; acc[0][1] += av.x * bv.y;
      acc[0][2] += av.x * bv.z; acc[0][3] += av.x * bv.w;
      acc[1][0] += av.y * bv.x; acc[1][1] += av.y * bv.y;
      acc[1][2] += av.y * bv.z; acc[1][3] += av.y * bv.w;
      acc[2][0] += av.z * bv.x; acc[2][1] += av.z * bv.y;
      acc[2][2] += av.z * bv.z; acc[2][3] += av.z * bv.w;
      acc[3][0] += av.w * bv.x; acc[3][1] += av.w * bv.y;
      acc[3][2] += av.w * bv.z; acc[3][3] += av.w * bv.w;
    }
    __syncthreads();
  }
#pragma unroll
  for (int i = 0; i < 4; ++i)
#pragma unroll
    for (int j = 0; j < 4; ++j)
      simp[((size_t)z * B + b0 + ty * 4 + i) * P + p0 + tx * 4 + j] =
          acc[i][j];
}

// ---------------------------------------------------------------------------
// Kernel 3 (select + gather merged): grid(B), block(1024).
// t<512: split-K reduce + alpha*beta scale + 4 Gumbel argmax rounds with
// in-register mask-out (bit-identical math to the verified r3 select).
// Then all 16 waves gather the 4 selected prompt rows (128 KB) -> out[b].
// Saves one launch boundary + the sidx round-trip.
// ---------------------------------------------------------------------------
__global__ __launch_bounds__(1024) void select_gather_kernel(
    const float* __restrict__ simp, const float* __restrict__ alpha,
    const float* __restrict__ beta, const float* __restrict__ gu,
    const float* __restrict__ prompt, float* __restrict__ out) {
  const int b = blockIdx.x;
  const int t = threadIdx.x;
  const int lane = t & 63, wv = t >> 6;

  __shared__ float wval[8];
  __shared__ int   widx[8];
  __shared__ int   ssel[TOPK];

  float c = 0.f;
  float g[TOPK];
  if (t < P) {
#pragma unroll
    for (int z = 0; z < KSPLIT; ++z)
      c += simp[((size_t)z * B + b) * P + t];
    c *= alpha[b] * beta[t];
#pragma unroll
    for (int i = 0; i < TOPK; ++i) {
      float u = gu[((size_t)i * B + b) * P + t];
      g[i] = -logf(-logf(u + 1e-10f) + 1e-10f);
    }
  }

  for (int i = 0; i < TOPK; ++i) {
    if (t < P) {
      float v = c + g[i];
      int idx = t;
      for (int off = 32; off > 0; off >>= 1) {
        float ov = __shfl_down(v, off, 64);
        int oi = __shfl_down(idx, off, 64);
        if (ov > v || (ov == v && oi < idx)) { v = ov; idx = oi; }
      }
      if (lane == 0) { wval[wv] = v; widx[wv] = idx; }
    }
    __syncthreads();
    if (t == 0) {
      float bv = wval[0]; int bi = widx[0];
#pragma unroll
      for (int k = 1; k < 8; ++k)
        if (wval[k] > bv || (wval[k] == bv && widx[k] < bi)) {
          bv = wval[k]; bi = widx[k];
        }
      ssel[i] = bi;
    }
    __syncthreads();
    if (t < P && t == ssel[i]) c -= 1000.0f;  // hard mask-out
  }

  // ---- gather: 16 waves copy 4 x 32 KB rows, bit-exact ----
#pragma unroll
  for (int i = 0; i < TOPK; ++i) {
    const int p = ssel[i];
    const float4* src = (const float4*)(prompt + (size_t)p * L * D);
    float4* dst = (float4*)(out + ((size_t)b * (TOPK * L) + i * L) * D);
    dst[t] = src[t];
    dst[t + 1024] = src[t + 1024];
  }
}

// ---------------------------------------------------------------------------
extern "C" void kernel_launch(void* const* d_in, const int* in_sizes, int n_in,
                              void* d_out, int out_size, void* d_ws,
                              size_t ws_size, hipStream_t stream) {
  const float* x_embed    = (const float*)d_in[0];  // [B,S,D]
  const float* prompt     = (const float*)d_in[1];  // [P,L,D]
  const float* prompt_key = (const float*)d_in[2];  // [P,D]
  const float* gumbel_u   = (const float*)d_in[3];  // [TOPK,B,P]
  float* out = (float*)d_out;                       // [B,TOPK*L,D]

  // ws layout (~5.3 MB): simp | qm | alpha | beta
  float* simp  = (float*)d_ws;                     // KSPLIT*B*P = 1048576 f
  float* qm    = simp + (size_t)KSPLIT * B * P;    // B*D        =  262144 f
  float* alpha = qm + (size_t)B * D;               // B
  float* beta  = alpha + B;                        // P

  query_norm_kernel<<<B, 1024, 0, stream>>>(x_embed, prompt_key, qm, alpha,
                                            beta);
  sim_kernel<<<dim3(B / 64, P / 64, KSPLIT), 256, 0, stream>>>(qm, prompt_key,
                                                               simp);
  select_gather_kernel<<<B, 1024, 0, stream>>>(simp, alpha, beta, gumbel_u,
                                               prompt, out);
}